// Round 5
// baseline (192.617 us; speedup 1.0000x reference)
//
#include <hip/hip_runtime.h>

#define DIM 768
#define NB  32
#define LQ  512
#define NV  128

typedef unsigned short u16;
typedef unsigned int   u32;
typedef __bf16 bf16x8 __attribute__((ext_vector_type(8)));
typedef float  f32x4  __attribute__((ext_vector_type(4)));
typedef u16    u16x8  __attribute__((ext_vector_type(8)));
typedef u16    u16x4  __attribute__((ext_vector_type(4)));

typedef __attribute__((address_space(1))) const void gvoid;
typedef __attribute__((address_space(3))) void       svoid;

__device__ __forceinline__ u16 f2bf(float f) {
    u32 u = __float_as_uint(f);
    return (u16)((u + 0x7FFFu + ((u >> 16) & 1u)) >> 16);   // RNE
}

__device__ __forceinline__ bf16x8 ld_frag(const u16* p) {
    return __builtin_bit_cast(bf16x8, *(const u16x8*)p);
}

__device__ __forceinline__ void gld16(const void* g, void* l) {
    __builtin_amdgcn_global_load_lds((gvoid*)g, (svoid*)l, 16, 0, 0);
}

// ---------------------------------------------------------------------------
// Fused prep, 3 block classes:
//   [0,36)            W2 = w_q^T @ w_k  (fp32 in, LDS-transpose staging, bf16 out)
//   [36, 36+6144)     lines fp32 -> bf16
//   [6180, 6180+384)  videos -> vt2 (PV B-frag order) + vbf (row-major bf16)
// ---------------------------------------------------------------------------
#define W2_BLK 36
#define NL_BLK 6144

__global__ __launch_bounds__(256) void prep_kernel(const float* __restrict__ lines,
                                                   const float* __restrict__ w_q,
                                                   const float* __restrict__ w_k,
                                                   const float* __restrict__ videos,
                                                   u16* __restrict__ lbf,
                                                   u16* __restrict__ w2b,
                                                   u16* __restrict__ vt2,
                                                   u16* __restrict__ vbf) {
    __shared__ union {
        u16 T[64][136];                             // vt transpose tile (17 KB)
        struct { u16 q[128][72]; u16 k[128][72]; } w2s;   // w2 staging (36 KB)
    } uL;
    const int bx = blockIdx.x;
    const int t  = threadIdx.x;

    if (bx < W2_BLK) {
        // ---- W2[d][d'] = sum_e w_q[e][d] * w_k[e][d'], 128x128 tile ----
        const int m0 = (bx / 6) * 128;
        const int n0 = (bx % 6) * 128;
        const int w    = t >> 6;
        const int lane = t & 63;
        const int quad = lane >> 4;
        const int ln   = lane & 15;
        const int wr   = (w >> 1) * 64;
        const int wc   = (w & 1) * 64;
        f32x4 acc[4][4] = {};
        for (int ks = 0; ks < 12; ++ks) {
            __syncthreads();
            const int e0 = ks * 64;
#pragma unroll
            for (int p = 0; p < 8; ++p) {           // 64 e-rows x 32 d-float4
                int f  = t + p * 256;
                int r  = f >> 5;                    // e row [0,64)
                int c4 = f & 31;                    // d chunk [0,32)
                float4 xq = *(const float4*)(w_q + (size_t)(e0 + r) * DIM + m0 + c4 * 4);
                float4 xk = *(const float4*)(w_k + (size_t)(e0 + r) * DIM + n0 + c4 * 4);
                uL.w2s.q[c4 * 4 + 0][r] = f2bf(xq.x);
                uL.w2s.q[c4 * 4 + 1][r] = f2bf(xq.y);
                uL.w2s.q[c4 * 4 + 2][r] = f2bf(xq.z);
                uL.w2s.q[c4 * 4 + 3][r] = f2bf(xq.w);
                uL.w2s.k[c4 * 4 + 0][r] = f2bf(xk.x);
                uL.w2s.k[c4 * 4 + 1][r] = f2bf(xk.y);
                uL.w2s.k[c4 * 4 + 2][r] = f2bf(xk.z);
                uL.w2s.k[c4 * 4 + 3][r] = f2bf(xk.w);
            }
            __syncthreads();
#pragma unroll
            for (int kk = 0; kk < 2; ++kk) {
                bf16x8 af[4], bfr[4];
#pragma unroll
                for (int i = 0; i < 4; ++i) af[i]  = ld_frag(&uL.w2s.q[wr + i * 16 + ln][kk * 32 + quad * 8]);
#pragma unroll
                for (int j = 0; j < 4; ++j) bfr[j] = ld_frag(&uL.w2s.k[wc + j * 16 + ln][kk * 32 + quad * 8]);
#pragma unroll
                for (int i = 0; i < 4; ++i)
#pragma unroll
                    for (int j = 0; j < 4; ++j)
                        acc[i][j] = __builtin_amdgcn_mfma_f32_16x16x32_bf16(af[i], bfr[j], acc[i][j], 0, 0, 0);
            }
        }
#pragma unroll
        for (int i = 0; i < 4; ++i)
#pragma unroll
            for (int j = 0; j < 4; ++j)
#pragma unroll
                for (int r = 0; r < 4; ++r)
                    w2b[(size_t)(m0 + wr + i * 16 + quad * 4 + r) * DIM + n0 + wc + j * 16 + ln] =
                        f2bf(acc[i][j][r]);
        return;
    }

    if (bx < W2_BLK + NL_BLK) {                     // ---- lines cvt ----
        size_t i = (size_t)(bx - W2_BLK) * 256 + t;
        float4 a = ((const float4*)lines)[i * 2];
        float4 b = ((const float4*)lines)[i * 2 + 1];
        u16x8 o = { f2bf(a.x), f2bf(a.y), f2bf(a.z), f2bf(a.w),
                    f2bf(b.x), f2bf(b.y), f2bf(b.z), f2bf(b.w) };
        ((u16x8*)lbf)[i] = o;
        return;
    }

    // ---- videos -> vt2 + vbf ----
    const int v  = bx - (W2_BLK + NL_BLK);          // [0, 384)
    const int b  = v / 12;
    const int d0 = (v % 12) * 64;
    const float* src = videos + (size_t)b * NV * DIM;
#pragma unroll
    for (int p = 0; p < 8; ++p) {
        int f  = t + p * 256;
        int vv = f >> 4;
        int c4 = f & 15;
        float4 x = *(const float4*)(src + (size_t)vv * DIM + d0 + c4 * 4);
        u16x4 o = { f2bf(x.x), f2bf(x.y), f2bf(x.z), f2bf(x.w) };
        uL.T[c4 * 4 + 0][vv] = o[0];
        uL.T[c4 * 4 + 1][vv] = o[1];
        uL.T[c4 * 4 + 2][vv] = o[2];
        uL.T[c4 * 4 + 3][vv] = o[3];
        *(u16x4*)(vbf + ((size_t)b * NV + vv) * DIM + d0 + c4 * 4) = o;
    }
    __syncthreads();
#pragma unroll
    for (int p = 0; p < 4; ++p) {
        int f  = t + p * 256;
        int dl = f >> 4;
        int v8 = f & 15;                            // = ks*4 + quad
        int d  = d0 + dl;
        int it = d >> 7, wv = (d >> 4) & 7, lnn = d & 15;
        int ks = v8 >> 2, qd = v8 & 3;
        int lane = qd * 16 + lnn;
        size_t off = ((((size_t)b * 6 + it) * 8 + wv) * 4 + ks) * 512 + lane * 8;
        *(u16x8*)(vt2 + off) = *(const u16x8*)&uL.T[dl][v8 * 8];
    }
}

// ---------------------------------------------------------------------------
// G[4096 x 768] = vbf[4096 x 768] @ W2^T, all bf16. 128x128 tile, BK=64,
// 8 waves, gld16 + XOR swizzle, XCD-affinity (6 n-tiles of one m-tile / XCD).
// ---------------------------------------------------------------------------
__global__ __launch_bounds__(512) void g_kernel(const u16* __restrict__ A,
                                                const u16* __restrict__ W,
                                                u16* __restrict__ C) {
    __shared__ u16 sA[128][64];
    __shared__ u16 sB[128][64];
    const int t    = threadIdx.x;
    const int w    = t >> 6;
    const int lane = t & 63;
    const int quad = lane >> 4;
    const int ln   = lane & 15;

    int m0, n0;
    {
        int i = blockIdx.x;                         // 192 blocks
        int xcd = i & 7, s = i >> 3;                // s in [0,24)
        m0 = ((s / 6) * 8 + xcd) * 128;             // 32 m-tiles
        n0 = (s % 6) * 128;
    }

    const int wr = (w >> 2) * 64;
    const int wc = (w & 3) * 32;
    const int srow   = lane >> 3;
    const int schunk = (lane & 7) ^ srow;

    f32x4 acc[4][2] = {};
#pragma unroll
    for (int ks = 0; ks < 12; ++ks) {
        __syncthreads();
#pragma unroll
        for (int p = 0; p < 2; ++p) {
            int rb = w * 16 + p * 8;
            gld16(A + (size_t)(m0 + rb + srow) * DIM + ks * 64 + schunk * 8, &sA[rb][0]);
            gld16(W + (size_t)(n0 + rb + srow) * DIM + ks * 64 + schunk * 8, &sB[rb][0]);
        }
        __syncthreads();
#pragma unroll
        for (int kk = 0; kk < 2; ++kk) {
            bf16x8 af[4], bfr[2];
#pragma unroll
            for (int i = 0; i < 4; ++i)
                af[i]  = ld_frag(&sA[wr + i * 16 + ln][((kk * 4 + quad) ^ (ln & 7)) * 8]);
#pragma unroll
            for (int j = 0; j < 2; ++j)
                bfr[j] = ld_frag(&sB[wc + j * 16 + ln][((kk * 4 + quad) ^ (ln & 7)) * 8]);
#pragma unroll
            for (int i = 0; i < 4; ++i)
#pragma unroll
                for (int j = 0; j < 2; ++j)
                    acc[i][j] = __builtin_amdgcn_mfma_f32_16x16x32_bf16(af[i], bfr[j], acc[i][j], 0, 0, 0);
        }
    }
#pragma unroll
    for (int i = 0; i < 4; ++i)
#pragma unroll
        for (int j = 0; j < 2; ++j)
#pragma unroll
            for (int r = 0; r < 4; ++r)
                C[(size_t)(m0 + wr + i * 16 + quad * 4 + r) * DIM + n0 + wc + j * 16 + ln] =
                    f2bf(acc[i][j][r]);
}

// ---------------------------------------------------------------------------
// Attention (unchanged structure): Q := lines bf16, K := G.
// ---------------------------------------------------------------------------
__global__ __launch_bounds__(512) void attn_kernel(const u16* __restrict__ Q,
                                                   const u16* __restrict__ K,
                                                   const u16* __restrict__ Vt2,
                                                   const int* __restrict__ mask,
                                                   float* __restrict__ out) {
    int b, l0;
    {
        int i = blockIdx.x;
        int xcd = i & 7, s = i >> 3;
        b  = (s >> 3) * 8 + xcd;
        l0 = (s & 7) * 64;
    }
    const int t    = threadIdx.x;
    const int w    = t >> 6;
    const int lane = t & 63;
    const int quad = lane >> 4;
    const int ln   = lane & 15;

    __shared__ union {
        struct { u16 q[64][64]; u16 k[128][64]; } st;
        float s[64][132];
    } uA;
    __shared__ union {
        struct { u16 q[64][64]; u16 k[128][64]; } st;
        u16 p[64][136];
    } uB;
    __shared__ float sBias[128];

    const u16* Qb = Q + ((size_t)b * LQ + l0) * DIM;
    const u16* Kb = K + (size_t)b * NV * DIM;
    if (t < NV) sBias[t] = mask[b * NV + t] ? 0.0f : -1e9f;

    const int srow   = lane >> 3;
    const int schunk = (lane & 7) ^ srow;

    auto stage = [&](int ks, int sel) {
        u16 (*q)[64] = sel ? uB.st.q : uA.st.q;
        u16 (*k)[64] = sel ? uB.st.k : uA.st.k;
        gld16(Qb + (size_t)(w * 8 + srow) * DIM + ks * 64 + schunk * 8, &q[w * 8][0]);
        gld16(Kb + (size_t)(w * 16 + srow) * DIM + ks * 64 + schunk * 8, &k[w * 16][0]);
        gld16(Kb + (size_t)(w * 16 + 8 + srow) * DIM + ks * 64 + schunk * 8, &k[w * 16 + 8][0]);
    };

    // ---- Phase 1: S = Q K^T ----
    f32x4 accS[4] = {};
    stage(0, 0);
#pragma unroll
    for (int ks = 0; ks < 12; ++ks) {
        __syncthreads();
        if (ks < 11) stage(ks + 1, (ks + 1) & 1);
        u16 (*q)[64] = (ks & 1) ? uB.st.q : uA.st.q;
        u16 (*k)[64] = (ks & 1) ? uB.st.k : uA.st.k;
#pragma unroll
        for (int kk = 0; kk < 2; ++kk) {
            bf16x8 bfr = ld_frag(&k[w * 16 + ln][((kk * 4 + quad) ^ (ln & 7)) * 8]);
#pragma unroll
            for (int i = 0; i < 4; ++i) {
                bf16x8 af = ld_frag(&q[i * 16 + ln][((kk * 4 + quad) ^ (ln & 7)) * 8]);
                accS[i] = __builtin_amdgcn_mfma_f32_16x16x32_bf16(af, bfr, accS[i], 0, 0, 0);
            }
        }
    }
    __syncthreads();
    const float scale = 0.03608439182435161f;       // 768^-0.5
#pragma unroll
    for (int i = 0; i < 4; ++i)
#pragma unroll
        for (int r = 0; r < 4; ++r)
            uA.s[i * 16 + quad * 4 + r][w * 16 + ln] = accS[i][r] * scale;
    __syncthreads();

    // ---- Phase 2: masked softmax ----
    {
        const int row = t >> 3, seg = t & 7;
        float vals[16];
        float mx = -3.0e38f;
#pragma unroll
        for (int c = 0; c < 4; ++c) {
            float4 x  = *(const float4*)&uA.s[row][seg * 16 + c * 4];
            float4 bz = *(const float4*)&sBias[seg * 16 + c * 4];
            float a0 = x.x + bz.x, a1 = x.y + bz.y, a2 = x.z + bz.z, a3 = x.w + bz.w;
            vals[c * 4 + 0] = a0; vals[c * 4 + 1] = a1;
            vals[c * 4 + 2] = a2; vals[c * 4 + 3] = a3;
            mx = fmaxf(mx, fmaxf(fmaxf(a0, a1), fmaxf(a2, a3)));
        }
        mx = fmaxf(mx, __shfl_xor(mx, 1));
        mx = fmaxf(mx, __shfl_xor(mx, 2));
        mx = fmaxf(mx, __shfl_xor(mx, 4));
        float sum = 0.0f;
#pragma unroll
        for (int c = 0; c < 16; ++c) { float e = __expf(vals[c] - mx); vals[c] = e; sum += e; }
        sum += __shfl_xor(sum, 1);
        sum += __shfl_xor(sum, 2);
        sum += __shfl_xor(sum, 4);
        const float inv = 1.0f / sum;
        __syncthreads();
#pragma unroll
        for (int h = 0; h < 2; ++h) {
            u16x8 pk;
#pragma unroll
            for (int e = 0; e < 8; ++e) pk[e] = f2bf(vals[h * 8 + e] * inv);
            *(u16x8*)&uB.p[row][seg * 16 + h * 8] = pk;
        }
    }
    __syncthreads();

    bf16x8 paf[4][4];
#pragma unroll
    for (int i = 0; i < 4; ++i)
#pragma unroll
        for (int ks = 0; ks < 4; ++ks)
            paf[i][ks] = ld_frag(&uB.p[i * 16 + ln][ks * 32 + quad * 8]);

    // ---- Phase 3: out = P @ V, no LDS, no barriers ----
    const u16* V2 = Vt2 + (size_t)b * 6 * 8 * 4 * 512;
    float*     Ob = out + ((size_t)b * LQ + l0) * DIM;
    for (int it = 0; it < 6; ++it) {
        f32x4 accO[4] = {};
#pragma unroll
        for (int ks = 0; ks < 4; ++ks) {
            bf16x8 bv = ld_frag(V2 + (((size_t)(it * 8 + w)) * 4 + ks) * 512 + lane * 8);
#pragma unroll
            for (int i = 0; i < 4; ++i)
                accO[i] = __builtin_amdgcn_mfma_f32_16x16x32_bf16(paf[i][ks], bv, accO[i], 0, 0, 0);
        }
#pragma unroll
        for (int i = 0; i < 4; ++i)
#pragma unroll
            for (int r = 0; r < 4; ++r)
                Ob[(size_t)(i * 16 + quad * 4 + r) * DIM + it * 128 + w * 16 + ln] = accO[i][r];
    }
}

// ---------------------------------------------------------------------------
extern "C" void kernel_launch(void* const* d_in, const int* in_sizes, int n_in,
                              void* d_out, int out_size, void* d_ws, size_t ws_size,
                              hipStream_t stream) {
    const float* lines  = (const float*)d_in[0];
    const float* videos = (const float*)d_in[1];
    const int*   mask   = (const int*)d_in[2];
    const float* w_q    = (const float*)d_in[3];
    const float* w_k    = (const float*)d_in[4];
    float*       out    = (float*)d_out;

    u16* gw  = (u16*)d_ws;                        // G: 4096x768 bf16 (6.3 MB)
    u16* vt2 = gw  + (size_t)NB * NV * DIM;       // 32x768x128 (frag order)
    u16* lbf = vt2 + (size_t)NB * DIM * NV;       // lines bf16 (25.2 MB)
    u16* vbf = lbf + (size_t)NB * LQ * DIM;       // videos bf16 (6.3 MB)
    u16* w2b = vbf + (size_t)NB * NV * DIM;       // W2 bf16 (1.2 MB)

    prep_kernel<<<W2_BLK + NL_BLK + 384, 256, 0, stream>>>(
        lines, w_q, w_k, videos, lbf, w2b, vt2, vbf);
    g_kernel   <<<192, 512, 0, stream>>>(vbf, w2b, gw);
    attn_kernel<<<256, 512, 0, stream>>>(lbf, gw, vt2, mask, out);
}

// Round 6
// 163.568 us; speedup vs baseline: 1.1776x; 1.1776x over previous
//
#include <hip/hip_runtime.h>

#define DIM 768
#define NB  32
#define LQ  512
#define NV  128

typedef unsigned short u16;
typedef unsigned int   u32;
typedef __bf16 bf16x8 __attribute__((ext_vector_type(8)));
typedef float  f32x4  __attribute__((ext_vector_type(4)));
typedef u16    u16x8  __attribute__((ext_vector_type(8)));
typedef u16    u16x4  __attribute__((ext_vector_type(4)));

typedef __attribute__((address_space(1))) const void gvoid;
typedef __attribute__((address_space(3))) void       svoid;

__device__ __forceinline__ u16 f2bf(float f) {
    u32 u = __float_as_uint(f);
    return (u16)((u + 0x7FFFu + ((u >> 16) & 1u)) >> 16);   // RNE
}

__device__ __forceinline__ bf16x8 ld_frag(const u16* p) {
    return __builtin_bit_cast(bf16x8, *(const u16x8*)p);
}

__device__ __forceinline__ void gld16(const void* g, void* l) {
    __builtin_amdgcn_global_load_lds((gvoid*)g, (svoid*)l, 16, 0, 0);
}

// ---------------------------------------------------------------------------
// Fused prep, 3 block classes (256 threads):
//   [0,144)        W2 partials: tile(36) x ksplit(4), atomicAdd fp32 into w2f
//   [144,+6144)    lines fp32 -> bf16
//   [6288,+384)    videos -> vt2 (PV B-frag order) + vbf (row-major bf16)
// ---------------------------------------------------------------------------
#define W2S    4
#define W2_BLK (36 * W2S)
#define NL_BLK 6144

__global__ __launch_bounds__(256) void prep_kernel(const float* __restrict__ lines,
                                                   const float* __restrict__ w_q,
                                                   const float* __restrict__ w_k,
                                                   const float* __restrict__ videos,
                                                   u16* __restrict__ lbf,
                                                   float* __restrict__ w2f,
                                                   u16* __restrict__ vt2,
                                                   u16* __restrict__ vbf) {
    __shared__ union {
        u16 T[64][136];                             // vt transpose tile
        struct { u16 q[128][72]; u16 k[128][72]; } w2s;   // W2 staging (36 KB)
    } uL;
    const int bx = blockIdx.x;
    const int t  = threadIdx.x;

    if (bx < W2_BLK) {
        // ---- partial W2[m][n] += sum_{e in chunk} wq[e][m]*wk[e][n] ----
        const int tile = bx / W2S, kc = bx % W2S;
        const int m0 = (tile / 6) * 128;
        const int n0 = (tile % 6) * 128;
        const int w    = t >> 6;
        const int lane = t & 63;
        const int quad = lane >> 4;
        const int ln   = lane & 15;
        const int wr   = (w >> 1) * 64;
        const int wc   = (w & 1) * 64;
        f32x4 acc[4][4] = {};
        for (int ks = kc * 3; ks < kc * 3 + 3; ++ks) {
            __syncthreads();
            const int e0 = ks * 64;
#pragma unroll
            for (int p = 0; p < 8; ++p) {           // 64 e-rows x 32 d-float4
                int f  = t + p * 256;
                int r  = f >> 5;                    // e row [0,64)
                int c4 = f & 31;                    // d chunk [0,32)
                float4 xq = *(const float4*)(w_q + (size_t)(e0 + r) * DIM + m0 + c4 * 4);
                float4 xk = *(const float4*)(w_k + (size_t)(e0 + r) * DIM + n0 + c4 * 4);
                // swizzled transpose write: chunk' = (r>>3) ^ ((row>>3)&7)
                int swz = ((r >> 3) ^ ((c4 >> 1) & 7)) * 8 + (r & 7);
                uL.w2s.q[c4 * 4 + 0][swz] = f2bf(xq.x);
                uL.w2s.q[c4 * 4 + 1][swz] = f2bf(xq.y);
                uL.w2s.q[c4 * 4 + 2][swz] = f2bf(xq.z);
                uL.w2s.q[c4 * 4 + 3][swz] = f2bf(xq.w);
                uL.w2s.k[c4 * 4 + 0][swz] = f2bf(xk.x);
                uL.w2s.k[c4 * 4 + 1][swz] = f2bf(xk.y);
                uL.w2s.k[c4 * 4 + 2][swz] = f2bf(xk.z);
                uL.w2s.k[c4 * 4 + 3][swz] = f2bf(xk.w);
            }
            __syncthreads();
#pragma unroll
            for (int kk = 0; kk < 2; ++kk) {
                bf16x8 af[4], bfr[4];
#pragma unroll
                for (int i = 0; i < 4; ++i) {
                    int row = wr + i * 16 + ln;
                    af[i]  = ld_frag(&uL.w2s.q[row][((kk * 4 + quad) ^ ((row >> 3) & 7)) * 8]);
                }
#pragma unroll
                for (int j = 0; j < 4; ++j) {
                    int row = wc + j * 16 + ln;
                    bfr[j] = ld_frag(&uL.w2s.k[row][((kk * 4 + quad) ^ ((row >> 3) & 7)) * 8]);
                }
#pragma unroll
                for (int i = 0; i < 4; ++i)
#pragma unroll
                    for (int j = 0; j < 4; ++j)
                        acc[i][j] = __builtin_amdgcn_mfma_f32_16x16x32_bf16(af[i], bfr[j], acc[i][j], 0, 0, 0);
            }
        }
#pragma unroll
        for (int i = 0; i < 4; ++i)
#pragma unroll
            for (int j = 0; j < 4; ++j)
#pragma unroll
                for (int r = 0; r < 4; ++r)
                    atomicAdd(&w2f[(size_t)(m0 + wr + i * 16 + quad * 4 + r) * DIM +
                                   n0 + wc + j * 16 + ln], acc[i][j][r]);
        return;
    }

    if (bx < W2_BLK + NL_BLK) {                     // ---- lines cvt ----
        size_t i = (size_t)(bx - W2_BLK) * 256 + t;
        float4 a = ((const float4*)lines)[i * 2];
        float4 b = ((const float4*)lines)[i * 2 + 1];
        u16x8 o = { f2bf(a.x), f2bf(a.y), f2bf(a.z), f2bf(a.w),
                    f2bf(b.x), f2bf(b.y), f2bf(b.z), f2bf(b.w) };
        ((u16x8*)lbf)[i] = o;
        return;
    }

    // ---- videos -> vt2 + vbf ----
    const int v  = bx - (W2_BLK + NL_BLK);          // [0, 384)
    const int b  = v / 12;
    const int d0 = (v % 12) * 64;
    const float* src = videos + (size_t)b * NV * DIM;
#pragma unroll
    for (int p = 0; p < 8; ++p) {
        int f  = t + p * 256;
        int vv = f >> 4;
        int c4 = f & 15;
        float4 x = *(const float4*)(src + (size_t)vv * DIM + d0 + c4 * 4);
        u16x4 o = { f2bf(x.x), f2bf(x.y), f2bf(x.z), f2bf(x.w) };
        uL.T[c4 * 4 + 0][vv] = o[0];
        uL.T[c4 * 4 + 1][vv] = o[1];
        uL.T[c4 * 4 + 2][vv] = o[2];
        uL.T[c4 * 4 + 3][vv] = o[3];
        *(u16x4*)(vbf + ((size_t)b * NV + vv) * DIM + d0 + c4 * 4) = o;
    }
    __syncthreads();
#pragma unroll
    for (int p = 0; p < 4; ++p) {
        int f  = t + p * 256;
        int dl = f >> 4;
        int v8 = f & 15;                            // = ks*4 + quad
        int d  = d0 + dl;
        int it = d >> 7, wv = (d >> 4) & 7, lnn = d & 15;
        int ks = v8 >> 2, qd = v8 & 3;
        int lane = qd * 16 + lnn;
        size_t off = ((((size_t)b * 6 + it) * 8 + wv) * 4 + ks) * 512 + lane * 8;
        *(u16x8*)(vt2 + off) = *(const u16x8*)&uL.T[dl][v8 * 8];
    }
}

// ---------------------------------------------------------------------------
// G[4096 x 768] = vbf @ M^T. A (vbf bf16) via gld16; B (w2f fp32) staged with
// inline convert into padded sB. 128x128 tile, BK=64, 8 waves, XCD-affinity.
// ---------------------------------------------------------------------------
__global__ __launch_bounds__(512) void g_kernel(const u16* __restrict__ A,
                                                const float* __restrict__ Wf,
                                                u16* __restrict__ C) {
    __shared__ u16 sA[128][64];                     // gld16 layout (unpadded)
    __shared__ u16 sB[128][72];                     // padded, swizzled converts
    const int t    = threadIdx.x;
    const int w    = t >> 6;
    const int lane = t & 63;
    const int quad = lane >> 4;
    const int ln   = lane & 15;

    int m0, n0;
    {
        int i = blockIdx.x;                         // 192 blocks
        int xcd = i & 7, s = i >> 3;
        m0 = ((s / 6) * 8 + xcd) * 128;
        n0 = (s % 6) * 128;
    }

    const int wr = (w >> 2) * 64;
    const int wc = (w & 3) * 32;
    const int srow   = lane >> 3;
    const int schunk = (lane & 7) ^ srow;

    f32x4 acc[4][2] = {};
#pragma unroll
    for (int ks = 0; ks < 12; ++ks) {
        __syncthreads();
#pragma unroll
        for (int p = 0; p < 2; ++p) {               // A: 128 rows via gld16
            int rb = w * 16 + p * 8;
            gld16(A + (size_t)(m0 + rb + srow) * DIM + ks * 64 + schunk * 8, &sA[rb][0]);
        }
#pragma unroll
        for (int p = 0; p < 4; ++p) {               // B: 128 rows x 64 fp32, convert
            int idx = t + p * 512;
            int row = idx >> 4, c4 = idx & 15;
            float4 x = *(const float4*)(Wf + (size_t)(n0 + row) * DIM + ks * 64 + c4 * 4);
            u16x4 o = { f2bf(x.x), f2bf(x.y), f2bf(x.z), f2bf(x.w) };
            int swz = ((c4 >> 1) ^ (row & 7)) * 8 + (c4 & 1) * 4;
            *(u16x4*)&sB[row][swz] = o;
        }
        __syncthreads();
#pragma unroll
        for (int kk = 0; kk < 2; ++kk) {
            bf16x8 af[4], bfr[2];
#pragma unroll
            for (int i = 0; i < 4; ++i)
                af[i]  = ld_frag(&sA[wr + i * 16 + ln][((kk * 4 + quad) ^ (ln & 7)) * 8]);
#pragma unroll
            for (int j = 0; j < 2; ++j)
                bfr[j] = ld_frag(&sB[wc + j * 16 + ln][((kk * 4 + quad) ^ (ln & 7)) * 8]);
#pragma unroll
            for (int i = 0; i < 4; ++i)
#pragma unroll
                for (int j = 0; j < 2; ++j)
                    acc[i][j] = __builtin_amdgcn_mfma_f32_16x16x32_bf16(af[i], bfr[j], acc[i][j], 0, 0, 0);
        }
    }
#pragma unroll
    for (int i = 0; i < 4; ++i)
#pragma unroll
        for (int j = 0; j < 2; ++j)
#pragma unroll
            for (int r = 0; r < 4; ++r)
                C[(size_t)(m0 + wr + i * 16 + quad * 4 + r) * DIM + n0 + wc + j * 16 + ln] =
                    f2bf(acc[i][j][r]);
}

// ---------------------------------------------------------------------------
// Attention: Q := lines bf16, K := G. XCD-swizzled, 256 blocks, 8 waves.
// ---------------------------------------------------------------------------
__global__ __launch_bounds__(512) void attn_kernel(const u16* __restrict__ Q,
                                                   const u16* __restrict__ K,
                                                   const u16* __restrict__ Vt2,
                                                   const int* __restrict__ mask,
                                                   float* __restrict__ out) {
    int b, l0;
    {
        int i = blockIdx.x;
        int xcd = i & 7, s = i >> 3;
        b  = (s >> 3) * 8 + xcd;
        l0 = (s & 7) * 64;
    }
    const int t    = threadIdx.x;
    const int w    = t >> 6;
    const int lane = t & 63;
    const int quad = lane >> 4;
    const int ln   = lane & 15;

    __shared__ union {
        struct { u16 q[64][64]; u16 k[128][64]; } st;
        float s[64][132];
    } uA;
    __shared__ union {
        struct { u16 q[64][64]; u16 k[128][64]; } st;
        u16 p[64][136];
    } uB;
    __shared__ float sBias[128];

    const u16* Qb = Q + ((size_t)b * LQ + l0) * DIM;
    const u16* Kb = K + (size_t)b * NV * DIM;
    if (t < NV) sBias[t] = mask[b * NV + t] ? 0.0f : -1e9f;

    const int srow   = lane >> 3;
    const int schunk = (lane & 7) ^ srow;

    auto stage = [&](int ks, int sel) {
        u16 (*q)[64] = sel ? uB.st.q : uA.st.q;
        u16 (*k)[64] = sel ? uB.st.k : uA.st.k;
        gld16(Qb + (size_t)(w * 8 + srow) * DIM + ks * 64 + schunk * 8, &q[w * 8][0]);
        gld16(Kb + (size_t)(w * 16 + srow) * DIM + ks * 64 + schunk * 8, &k[w * 16][0]);
        gld16(Kb + (size_t)(w * 16 + 8 + srow) * DIM + ks * 64 + schunk * 8, &k[w * 16 + 8][0]);
    };

    // ---- Phase 1: S = Q K^T ----
    f32x4 accS[4] = {};
    stage(0, 0);
#pragma unroll
    for (int ks = 0; ks < 12; ++ks) {
        __syncthreads();
        if (ks < 11) stage(ks + 1, (ks + 1) & 1);
        u16 (*q)[64] = (ks & 1) ? uB.st.q : uA.st.q;
        u16 (*k)[64] = (ks & 1) ? uB.st.k : uA.st.k;
#pragma unroll
        for (int kk = 0; kk < 2; ++kk) {
            bf16x8 bfr = ld_frag(&k[w * 16 + ln][((kk * 4 + quad) ^ (ln & 7)) * 8]);
#pragma unroll
            for (int i = 0; i < 4; ++i) {
                bf16x8 af = ld_frag(&q[i * 16 + ln][((kk * 4 + quad) ^ (ln & 7)) * 8]);
                accS[i] = __builtin_amdgcn_mfma_f32_16x16x32_bf16(af, bfr, accS[i], 0, 0, 0);
            }
        }
    }
    __syncthreads();
    const float scale = 0.03608439182435161f;       // 768^-0.5
#pragma unroll
    for (int i = 0; i < 4; ++i)
#pragma unroll
        for (int r = 0; r < 4; ++r)
            uA.s[i * 16 + quad * 4 + r][w * 16 + ln] = accS[i][r] * scale;
    __syncthreads();

    // ---- Phase 2: masked softmax ----
    {
        const int row = t >> 3, seg = t & 7;
        float vals[16];
        float mx = -3.0e38f;
#pragma unroll
        for (int c = 0; c < 4; ++c) {
            float4 x  = *(const float4*)&uA.s[row][seg * 16 + c * 4];
            float4 bz = *(const float4*)&sBias[seg * 16 + c * 4];
            float a0 = x.x + bz.x, a1 = x.y + bz.y, a2 = x.z + bz.z, a3 = x.w + bz.w;
            vals[c * 4 + 0] = a0; vals[c * 4 + 1] = a1;
            vals[c * 4 + 2] = a2; vals[c * 4 + 3] = a3;
            mx = fmaxf(mx, fmaxf(fmaxf(a0, a1), fmaxf(a2, a3)));
        }
        mx = fmaxf(mx, __shfl_xor(mx, 1));
        mx = fmaxf(mx, __shfl_xor(mx, 2));
        mx = fmaxf(mx, __shfl_xor(mx, 4));
        float sum = 0.0f;
#pragma unroll
        for (int c = 0; c < 16; ++c) { float e = __expf(vals[c] - mx); vals[c] = e; sum += e; }
        sum += __shfl_xor(sum, 1);
        sum += __shfl_xor(sum, 2);
        sum += __shfl_xor(sum, 4);
        const float inv = 1.0f / sum;
        __syncthreads();
#pragma unroll
        for (int h = 0; h < 2; ++h) {
            u16x8 pk;
#pragma unroll
            for (int e = 0; e < 8; ++e) pk[e] = f2bf(vals[h * 8 + e] * inv);
            *(u16x8*)&uB.p[row][seg * 16 + h * 8] = pk;
        }
    }
    __syncthreads();

    bf16x8 paf[4][4];
#pragma unroll
    for (int i = 0; i < 4; ++i)
#pragma unroll
        for (int ks = 0; ks < 4; ++ks)
            paf[i][ks] = ld_frag(&uB.p[i * 16 + ln][ks * 32 + quad * 8]);

    // ---- Phase 3: out = P @ V, no LDS, no barriers ----
    const u16* V2 = Vt2 + (size_t)b * 6 * 8 * 4 * 512;
    float*     Ob = out + ((size_t)b * LQ + l0) * DIM;
    for (int it = 0; it < 6; ++it) {
        f32x4 accO[4] = {};
#pragma unroll
        for (int ks = 0; ks < 4; ++ks) {
            bf16x8 bv = ld_frag(V2 + (((size_t)(it * 8 + w)) * 4 + ks) * 512 + lane * 8);
#pragma unroll
            for (int i = 0; i < 4; ++i)
                accO[i] = __builtin_amdgcn_mfma_f32_16x16x32_bf16(paf[i][ks], bv, accO[i], 0, 0, 0);
        }
#pragma unroll
        for (int i = 0; i < 4; ++i)
#pragma unroll
            for (int r = 0; r < 4; ++r)
                Ob[(size_t)(i * 16 + quad * 4 + r) * DIM + it * 128 + w * 16 + ln] = accO[i][r];
    }
}

// ---------------------------------------------------------------------------
extern "C" void kernel_launch(void* const* d_in, const int* in_sizes, int n_in,
                              void* d_out, int out_size, void* d_ws, size_t ws_size,
                              hipStream_t stream) {
    const float* lines  = (const float*)d_in[0];
    const float* videos = (const float*)d_in[1];
    const int*   mask   = (const int*)d_in[2];
    const float* w_q    = (const float*)d_in[3];
    const float* w_k    = (const float*)d_in[4];
    float*       out    = (float*)d_out;

    u16*   gw  = (u16*)d_ws;                      // G: 4096x768 bf16 (6.3 MB)
    u16*   vt2 = gw  + (size_t)NB * NV * DIM;     // 32x768x128 (frag order)
    u16*   lbf = vt2 + (size_t)NB * DIM * NV;     // lines bf16 (25.2 MB)
    u16*   vbf = lbf + (size_t)NB * LQ * DIM;     // videos bf16 (6.3 MB)
    float* w2f = (float*)(vbf + (size_t)NB * NV * DIM);  // M fp32 (2.25 MB)

    hipMemsetAsync(w2f, 0, (size_t)DIM * DIM * sizeof(float), stream);
    prep_kernel<<<W2_BLK + NL_BLK + 384, 256, 0, stream>>>(
        lines, w_q, w_k, videos, lbf, w2f, vt2, vbf);
    g_kernel   <<<192, 512, 0, stream>>>(vbf, w2f, gw);
    attn_kernel<<<256, 512, 0, stream>>>(lbf, gw, vt2, mask, out);
}